// Round 1
// baseline (1526.780 us; speedup 1.0000x reference)
//
#include <hip/hip_runtime.h>

#define N_NODES 100000
#define N_EDGES 6400000
#define IN_CH   128
#define HID     32

// ---------- ws layout (bytes) ----------
#define O_FLAG   0u
#define O_DINV   256u
#define O_CNT    400384u
#define O_ROWS   800512u
#define O_CURS   1200640u
#define O_BSUM   1600768u
#define O_CSR    1601280u
#define O_HS     27201280u
#define O_H1     40001280u
// total ~52.8 MB

// Detect whether edge_index buffer is int64 (high words all zero) or int32.
__global__ void k_detect(const unsigned int* e, int* flag) {
    __shared__ int any;
    if (threadIdx.x == 0) any = 0;
    __syncthreads();
    int acc = 0;
    for (int i = threadIdx.x; i < 4096; i += 256)
        acc |= (e[2 * i + 1] != 0u);
    if (acc) atomicOr(&any, 1);
    __syncthreads();
    if (threadIdx.x == 0) *flag = any ? 0 : 1;   // 1 => int64
}

__device__ __forceinline__ int eload(const int* e, int is64, long long idx) {
    return is64 ? e[2 * (size_t)idx] : e[(size_t)idx];
}

__global__ void k_count(const int* e, const int* flag, int* cnt) {
    int is64 = *flag;
    long long i = (long long)blockIdx.x * blockDim.x + threadIdx.x;
    if (i >= N_EDGES) return;
    int dst = eload(e, is64, N_EDGES + i);
    atomicAdd(&cnt[dst], 1);
}

__global__ void k_scanA(const int* cnt, int* bsum) {
    __shared__ int lds[1024];
    int i = blockIdx.x * 1024 + threadIdx.x;
    int v = (i < N_NODES) ? cnt[i] : 0;
    lds[threadIdx.x] = v;
    __syncthreads();
    for (int off = 512; off; off >>= 1) {
        if (threadIdx.x < off) lds[threadIdx.x] += lds[threadIdx.x + off];
        __syncthreads();
    }
    if (threadIdx.x == 0) bsum[blockIdx.x] = lds[0];
}

__global__ void k_scanB(int* bsum, int nb) {   // single block of 128
    __shared__ int lds[128];
    int v = (threadIdx.x < nb) ? bsum[threadIdx.x] : 0;
    lds[threadIdx.x] = v;
    __syncthreads();
    for (int off = 1; off < 128; off <<= 1) {
        int t = (threadIdx.x >= off) ? lds[threadIdx.x - off] : 0;
        __syncthreads();
        lds[threadIdx.x] += t;
        __syncthreads();
    }
    if (threadIdx.x < nb) bsum[threadIdx.x] = lds[threadIdx.x] - v; // exclusive
}

__global__ void k_scanC(const int* cnt, const int* bsum, int* rows, int* cursor, float* dinv) {
    __shared__ int lds[1024];
    int i = blockIdx.x * 1024 + threadIdx.x;
    int v = (i < N_NODES) ? cnt[i] : 0;
    lds[threadIdx.x] = v;
    __syncthreads();
    for (int off = 1; off < 1024; off <<= 1) {
        int t = (threadIdx.x >= off) ? lds[threadIdx.x - off] : 0;
        __syncthreads();
        lds[threadIdx.x] += t;
        __syncthreads();
    }
    if (i < N_NODES) {
        int excl = lds[threadIdx.x] - v + bsum[blockIdx.x];
        rows[i]   = excl;
        cursor[i] = excl;
        dinv[i]   = rsqrtf((float)(v + 1));   // +1 self loop
    }
}

__global__ void k_fill(const int* e, const int* flag, int* cursor, int* csr) {
    int is64 = *flag;
    long long i = (long long)blockIdx.x * blockDim.x + threadIdx.x;
    if (i >= N_EDGES) return;
    int src = eload(e, is64, i);
    int dst = eload(e, is64, N_EDGES + i);
    int pos = atomicAdd(&cursor[dst], 1);
    csr[pos] = src;
}

// hs[i][c] = dinv[i] * sum_k x[i][k] * W1[k][c]
__launch_bounds__(256)
__global__ void k_gemm1(const float* __restrict__ x, const float* __restrict__ W1,
                        const float* __restrict__ dinv, float* __restrict__ hs) {
    __shared__ float w[IN_CH * HID];
    for (int i = threadIdx.x; i < IN_CH * HID; i += 256) w[i] = W1[i];
    __syncthreads();
    int lane = threadIdx.x & 31;
    int node = blockIdx.x * 8 + (threadIdx.x >> 5);
    const float4* xr = (const float4*)(x + (size_t)node * IN_CH);
    float acc = 0.f;
#pragma unroll
    for (int k4 = 0; k4 < IN_CH / 4; ++k4) {
        float4 xv = xr[k4];
        acc += xv.x * w[(k4 * 4 + 0) * HID + lane];
        acc += xv.y * w[(k4 * 4 + 1) * HID + lane];
        acc += xv.z * w[(k4 * 4 + 2) * HID + lane];
        acc += xv.w * w[(k4 * 4 + 3) * HID + lane];
    }
    hs[(size_t)node * HID + lane] = acc * dinv[node];
}

// h1[i][c] = relu(dinv[i]*(hs[i][c] + sum_incoming hs[src][c]) + b1[c])
__launch_bounds__(256)
__global__ void k_agg1(const float* __restrict__ hs, const int* __restrict__ csr,
                       const int* __restrict__ rows, const int* __restrict__ cnt,
                       const float* __restrict__ dinv, const float* __restrict__ b1,
                       float* __restrict__ h1) {
    int lane = threadIdx.x & 31;
    int node = blockIdx.x * 8 + (threadIdx.x >> 5);
    float s = hs[(size_t)node * HID + lane];     // self loop
    int start = rows[node], len = cnt[node];
    const int* cs = csr + start;
    for (int j = 0; j < len; ++j) {
        int src = cs[j];
        s += hs[(size_t)src * HID + lane];
    }
    float v = s * dinv[node] + b1[lane];
    h1[(size_t)node * HID + lane] = fmaxf(v, 0.f);
}

// hs2[i][c] = dinv[i] * sum_k h1[i][k] * W2[k][c]
__launch_bounds__(256)
__global__ void k_gemm2(const float* __restrict__ h1, const float* __restrict__ W2,
                        const float* __restrict__ dinv, float* __restrict__ hs2) {
    __shared__ float w[HID * HID];
    for (int i = threadIdx.x; i < HID * HID; i += 256) w[i] = W2[i];
    __syncthreads();
    int lane = threadIdx.x & 31;
    int node = blockIdx.x * 8 + (threadIdx.x >> 5);
    const float* hr = h1 + (size_t)node * HID;
    float acc = 0.f;
#pragma unroll
    for (int k = 0; k < HID; ++k) acc += hr[k] * w[k * HID + lane];
    hs2[(size_t)node * HID + lane] = acc * dinv[node];
}

// conv2 aggregation + relu + MLP head, fused
__launch_bounds__(256)
__global__ void k_agg2(const float* __restrict__ hs2, const int* __restrict__ csr,
                       const int* __restrict__ rows, const int* __restrict__ cnt,
                       const float* __restrict__ dinv, const float* __restrict__ b2,
                       const float* __restrict__ Wl1, const float* __restrict__ bl1,
                       const float* __restrict__ Wl2, const float* __restrict__ bl2,
                       float* __restrict__ out) {
    __shared__ float wl1[HID * HID];
    __shared__ float h2s[8][HID];
    for (int i = threadIdx.x; i < HID * HID; i += 256) wl1[i] = Wl1[i];
    __syncthreads();
    int lane = threadIdx.x & 31;
    int g = threadIdx.x >> 5;
    int node = blockIdx.x * 8 + g;
    float s = hs2[(size_t)node * HID + lane];
    int start = rows[node], len = cnt[node];
    const int* cs = csr + start;
    for (int j = 0; j < len; ++j) {
        int src = cs[j];
        s += hs2[(size_t)src * HID + lane];
    }
    float h2 = fmaxf(s * dinv[node] + b2[lane], 0.f);
    h2s[g][lane] = h2;
    __syncthreads();
    float a = bl1[lane];
#pragma unroll
    for (int k = 0; k < HID; ++k) a += h2s[g][k] * wl1[k * HID + lane];
    float h3 = fmaxf(a, 0.f);
    float o = h3 * Wl2[lane];
#pragma unroll
    for (int off = 16; off; off >>= 1) o += __shfl_down(o, off, 32);
    if (lane == 0) out[node] = o + *bl2;
}

extern "C" void kernel_launch(void* const* d_in, const int* in_sizes, int n_in,
                              void* d_out, int out_size, void* d_ws, size_t ws_size,
                              hipStream_t stream) {
    const float* x   = (const float*)d_in[0];
    const int*   e   = (const int*)d_in[1];
    const float* W1  = (const float*)d_in[2];
    const float* b1  = (const float*)d_in[3];
    const float* W2  = (const float*)d_in[4];
    const float* b2  = (const float*)d_in[5];
    const float* Wl1 = (const float*)d_in[6];
    const float* bl1 = (const float*)d_in[7];
    const float* Wl2 = (const float*)d_in[8];
    const float* bl2 = (const float*)d_in[9];
    float* out = (float*)d_out;

    char* w = (char*)d_ws;
    int*   flag   = (int*)(w + O_FLAG);
    float* dinv   = (float*)(w + O_DINV);
    int*   cnt    = (int*)(w + O_CNT);
    int*   rows   = (int*)(w + O_ROWS);
    int*   cursor = (int*)(w + O_CURS);
    int*   bsum   = (int*)(w + O_BSUM);
    int*   csr    = (int*)(w + O_CSR);
    float* hs     = (float*)(w + O_HS);
    float* h1     = (float*)(w + O_H1);
    float* hs2    = hs;   // reuse after conv1 aggregation

    const int NB_SCAN = (N_NODES + 1023) / 1024;       // 98
    const int NB_EDGE = (N_EDGES + 255) / 256;         // 25000
    const int NB_NODE = N_NODES / 8;                   // 12500 (exact)

    hipMemsetAsync(cnt, 0, (size_t)N_NODES * 4, stream);
    k_detect<<<1, 256, 0, stream>>>((const unsigned int*)e, flag);
    k_count<<<NB_EDGE, 256, 0, stream>>>(e, flag, cnt);
    k_scanA<<<NB_SCAN, 1024, 0, stream>>>(cnt, bsum);
    k_scanB<<<1, 128, 0, stream>>>(bsum, NB_SCAN);
    k_scanC<<<NB_SCAN, 1024, 0, stream>>>(cnt, bsum, rows, cursor, dinv);
    k_fill<<<NB_EDGE, 256, 0, stream>>>(e, flag, cursor, csr);

    k_gemm1<<<NB_NODE, 256, 0, stream>>>(x, W1, dinv, hs);
    k_agg1<<<NB_NODE, 256, 0, stream>>>(hs, csr, rows, cnt, dinv, b1, h1);
    k_gemm2<<<NB_NODE, 256, 0, stream>>>(h1, W2, dinv, hs2);
    k_agg2<<<NB_NODE, 256, 0, stream>>>(hs2, csr, rows, cnt, dinv, b2,
                                        Wl1, bl1, Wl2, bl2, out);
}